// Round 2
// baseline (484.809 us; speedup 1.0000x reference)
//
#include <hip/hip_runtime.h>
#include <stdint.h>

// AttentionModule: S=512, B=64, H=1024. Inputs f32, output f32.
// R10: gemm_bf tri-buffered prefetch-depth-2 with counted vmcnt(4) raw
//      barriers (loads stay in flight across barriers), XOR-swizzled LDS
//      (kills the 8-way ds_read_b128 bank conflict), epilogue U from L2.
//   init: scores=0, U=b_attn broadcast
//   cvt_all: enc/Wa_right/Wc -> bf16 (one launch)
//   gemm_u: split-K(4) atomicAdd into U
//   mode-1: scores += sum_j tanh(enc@Wa_r.T + U)*W_attn2   (m-fast grid)
//   applied: fused softmax + weighted sum + acat build + zero out_acc
//   mode-3: out_acc += acat @ Wc.T (+ b_comb on z==0), split-K(4)
//   tanh:   out = tanh(out_acc)

typedef __attribute__((ext_vector_type(8))) short bf16x8;
typedef __attribute__((ext_vector_type(4))) float f32x4;

__device__ __forceinline__ float bf2f(uint16_t u) {
  return __uint_as_float(((uint32_t)u) << 16);
}
__device__ __forceinline__ uint16_t f2bf(float x) {
  uint32_t u = __float_as_uint(x);
  u += 0x7fffu + ((u >> 16) & 1u);   // RNE
  return (uint16_t)(u >> 16);
}
__device__ __forceinline__ uint32_t pk2(float a, float b) {
  return (uint32_t)f2bf(a) | ((uint32_t)f2bf(b) << 16);
}
__device__ __forceinline__ uint4 cvt8(const float* __restrict__ p) {
  const float4 a = *(const float4*)p;
  const float4 b = *(const float4*)(p + 4);
  uint4 r;
  r.x = pk2(a.x, a.y); r.y = pk2(a.z, a.w);
  r.z = pk2(b.x, b.y); r.w = pk2(b.z, b.w);
  return r;
}
// tanh(x) = 1 - 2/(exp(2x)+1)
__device__ __forceinline__ float tanh_fast(float x) {
  const float e = __expf(2.f * x);
  return __builtin_fmaf(-2.f, __builtin_amdgcn_rcpf(e + 1.f), 1.f);
}
__device__ __forceinline__ void load16(const uint16_t* g, uint16_t* l) {
  __builtin_amdgcn_global_load_lds(
      (const __attribute__((address_space(1))) void*)g,
      (__attribute__((address_space(3))) void*)l, 16, 0, 0);
}

// scores = 0 (32768), U[b*2048+j] = b_attn[j] (131072). 128 blocks x 256.
__global__ __launch_bounds__(256)
void init_kernel(float* __restrict__ scores, float* __restrict__ U,
                 const float* __restrict__ ba) {
  const int tid = blockIdx.x * 256 + threadIdx.x;   // [0, 32768)
  scores[tid] = 0.f;
#pragma unroll
  for (int k = 0; k < 4; ++k) {
    const int i = tid * 4 + k;
    U[i] = ba[i & 2047];
  }
}

// one-shot converts: enc (4194304 u4) | Wa right half (262144 u4) | Wc (262144 u4)
__global__ __launch_bounds__(256)
void cvt_all_kernel(const float* __restrict__ enc, const float* __restrict__ Wa,
                    const float* __restrict__ Wc,
                    uint16_t* __restrict__ enc_bf, uint16_t* __restrict__ Wa_bf,
                    uint16_t* __restrict__ Wc_bf) {
  const int stride = gridDim.x * 256;
  for (int idx = blockIdx.x * 256 + threadIdx.x; idx < 4718592; idx += stride) {
    if (idx < 4194304) {
      ((uint4*)enc_bf)[idx] = cvt8(enc + (size_t)idx * 8);
    } else if (idx < 4456448) {
      const int k = idx - 4194304;
      const int j = k >> 7, c8 = k & 127;
      ((uint4*)Wa_bf)[k] = cvt8(Wa + (size_t)j * 2048 + 1024 + c8 * 8);
    } else {
      const int k = idx - 4456448;
      ((uint4*)Wc_bf)[k] = cvt8(Wc + (size_t)k * 8);
    }
  }
}

// split-K U-GEMM: U[b,j] += hidden[b,:]@W_attn[j,:1024].T over K-slice.
// grid (16 n-blocks, 4 k-splits); U prefilled with bias by init_kernel.
__global__ __launch_bounds__(256)
void gemm_u_kernel(const float* __restrict__ A, const float* __restrict__ B32,
                   float* __restrict__ U) {
  __shared__ __align__(16) uint16_t sA[128 * 32];
  __shared__ __align__(16) uint16_t sB[128 * 32];
  const int t = threadIdx.x, lane = t & 63, wave = t >> 6;
  const int wm = wave >> 1, wn = wave & 1;
  const int bn0 = blockIdx.x * 128;
  const int kbase = blockIdx.y * 256;
  const int srow = t >> 2, scol = (t & 3) * 8;
  const int ar0 = min(srow, 63), ar1 = min(64 + srow, 63);
  f32x4 acc[4][4];
#pragma unroll
  for (int i = 0; i < 4; ++i)
#pragma unroll
    for (int j = 0; j < 4; ++j) acc[i][j] = (f32x4){0.f, 0.f, 0.f, 0.f};
  const int mrow = wm * 64 + (lane & 15);
  const int nrow = wn * 64 + (lane & 15);
  const int kq = (lane >> 4) * 8;
  for (int kk = 0; kk < 8; ++kk) {
    const int k0 = kbase + (kk << 5);
    const uint4 va0 = cvt8(A + (size_t)ar0 * 1024 + scol + k0);
    const uint4 va1 = cvt8(A + (size_t)ar1 * 1024 + scol + k0);
    const uint4 vb0 = cvt8(B32 + (size_t)(bn0 + srow) * 2048 + scol + k0);
    const uint4 vb1 = cvt8(B32 + (size_t)(bn0 + 64 + srow) * 2048 + scol + k0);
    __syncthreads();
    *(uint4*)&sA[t * 8] = va0;
    *(uint4*)&sA[2048 + t * 8] = va1;
    *(uint4*)&sB[t * 8] = vb0;
    *(uint4*)&sB[2048 + t * 8] = vb1;
    __syncthreads();
    bf16x8 af[4], bfr[4];
#pragma unroll
    for (int i = 0; i < 4; ++i) af[i] = *(const bf16x8*)&sA[(mrow + i * 16) * 32 + kq];
#pragma unroll
    for (int j = 0; j < 4; ++j) bfr[j] = *(const bf16x8*)&sB[(nrow + j * 16) * 32 + kq];
#pragma unroll
    for (int i = 0; i < 4; ++i)
#pragma unroll
      for (int j = 0; j < 4; ++j)
        acc[i][j] = __builtin_amdgcn_mfma_f32_16x16x32_bf16(af[i], bfr[j], acc[i][j], 0, 0, 0);
  }
  const int colb = lane & 15, rquad = lane >> 4;
#pragma unroll
  for (int i = 0; i < 4; ++i)
#pragma unroll
    for (int r = 0; r < 4; ++r) {
      const int gm = wm * 64 + i * 16 + rquad * 4 + r;
      if (gm < 64) {
#pragma unroll
        for (int j = 0; j < 4; ++j) {
          const int gn = bn0 + wn * 64 + j * 16 + colb;
          atomicAdd(&U[gm * 2048 + gn], acc[i][j][r]);
        }
      }
    }
}

// ---- bf16 GEMM, tri-buffered global_load_lds, prefetch depth 2, counted
// vmcnt(4) + raw s_barrier (tile t+1's loads drained; t+2's stay in flight).
// LDS tiles are [128][32] bf16 with source/read XOR swizzle:
//   stored chunk kc at row r holds global 8-elem chunk kc ^ ((r>>1)&3)
//   -> 16-row fragment reads spread over all 32 banks (2-way, free).
// bm0 = blockIdx.x*128 (fast dim -> consecutive blocks share B-tile in L2)
// MODE 1: atomicAdd(scores[gm], sum_n tanh(acc + U[gm&63,gn]) * w2[gn])
// MODE 3: split-K over blockIdx.z (K-slice 512); atomicAdd(outf, acc [+bias])
template <int MODE>
__global__ __launch_bounds__(256)
void gemm_bf_kernel(const uint16_t* __restrict__ A, int lda,
                    const uint16_t* __restrict__ Bm, int ldb,
                    int M, int K,
                    float* __restrict__ outf,
                    const float* __restrict__ Ubias,
                    const float* __restrict__ bias) {
  __shared__ __align__(16) uint16_t lds[3][2][4096];  // 48 KB tri-buffer

  const int t = threadIdx.x, lane = t & 63, wave = t >> 6;
  const int wm = wave >> 1, wn = wave & 1;
  const int bm0 = blockIdx.x * 128;   // m fast
  const int bn0 = blockIdx.y * 128;   // j slow
  const int kbase = (MODE == 3) ? (int)blockIdx.z * 512 : 0;
  const int nt = ((MODE == 3) ? 512 : K) >> 5;

  // staging map: operand tile = 512 slots of 16B; thread covers slots
  // s = q*256 + t (q=0,1). slot -> r=s>>2, kc=s&3, global chunk kc^((r>>1)&3).
  const uint16_t* gpA[2];
  const uint16_t* gpB[2];
  int sb[2];
#pragma unroll
  for (int q = 0; q < 2; ++q) {
    const int s = q * 256 + t;
    const int r = s >> 2, kc = s & 3;
    const int g = kc ^ ((r >> 1) & 3);
    gpA[q] = A + (size_t)min(bm0 + r, M - 1) * lda + kbase + g * 8;
    gpB[q] = Bm + (size_t)(bn0 + r) * ldb + kbase + g * 8;
    sb[q] = (q * 256 + wave * 64) * 8;   // wave-uniform LDS base (elems)
  }

  f32x4 acc[4][4];
#pragma unroll
  for (int i = 0; i < 4; ++i)
#pragma unroll
    for (int j = 0; j < 4; ++j) acc[i][j] = (f32x4){0.f, 0.f, 0.f, 0.f};

  // fragment read offsets: row = wX*64 + i*16 + (lane&15), stored col =
  // kq ^ swz with swz = ((lane>>1)&3)<<3 (row bits 1-2, constant over i).
  const int swz = ((lane >> 1) & 3) << 3;
  const int kq = ((lane >> 4) * 8) ^ swz;
  const int aoff = (wm * 64 + (lane & 15)) * 32 + kq;
  const int boff = (wn * 64 + (lane & 15)) * 32 + kq;

  // prologue: stage tiles 0,1 into bufs 0,1; wait tile0 (vmcnt 4 = tile1 in flight)
#pragma unroll
  for (int q = 0; q < 2; ++q) {
    load16(gpA[q], &lds[0][0][sb[q]]);
    load16(gpB[q], &lds[0][1][sb[q]]);
  }
#pragma unroll
  for (int q = 0; q < 2; ++q) {
    load16(gpA[q] + 32, &lds[1][0][sb[q]]);
    load16(gpB[q] + 32, &lds[1][1][sb[q]]);
  }
  asm volatile("s_waitcnt vmcnt(4)" ::: "memory");
  __builtin_amdgcn_s_barrier();

  int cur = 0, nx2 = 2;
  for (int kt = 0; kt < nt; ++kt) {
    // stage tile kt+2 (clamped re-stage of last tile in the tail: target
    // buffer was last read at kt-1, so it is always safe to overwrite)
    const int kpre = (kt + 2 < nt) ? (kt + 2) * 32 : (nt - 1) * 32;
#pragma unroll
    for (int q = 0; q < 2; ++q) {
      load16(gpA[q] + kpre, &lds[nx2][0][sb[q]]);
      load16(gpB[q] + kpre, &lds[nx2][1][sb[q]]);
    }
    const uint16_t* sA = lds[cur][0];
    const uint16_t* sB = lds[cur][1];
    bf16x8 af[4], bfr[4];
#pragma unroll
    for (int i = 0; i < 4; ++i) af[i] = *(const bf16x8*)&sA[aoff + i * 512];
#pragma unroll
    for (int j = 0; j < 4; ++j) bfr[j] = *(const bf16x8*)&sB[boff + j * 512];
#pragma unroll
    for (int i = 0; i < 4; ++i)
#pragma unroll
      for (int j = 0; j < 4; ++j)
        acc[i][j] = __builtin_amdgcn_mfma_f32_16x16x32_bf16(af[i], bfr[j], acc[i][j], 0, 0, 0);
    // drain tile kt+1's loads only; kt+2's 4 loads stay in flight
    asm volatile("s_waitcnt vmcnt(4)" ::: "memory");
    __builtin_amdgcn_s_barrier();
    cur = (cur == 2) ? 0 : cur + 1;
    nx2 = (nx2 == 2) ? 0 : nx2 + 1;
  }
  // don't let LDS-DMA outlive this block's LDS allocation
  asm volatile("s_waitcnt vmcnt(0)" ::: "memory");

  const int colb = lane & 15, rquad = lane >> 4;
  if (MODE == 1) {
    float w2f[4];
#pragma unroll
    for (int j = 0; j < 4; ++j) w2f[j] = bias[bn0 + wn * 64 + j * 16 + colb];
#pragma unroll
    for (int i = 0; i < 4; ++i) {
#pragma unroll
      for (int r = 0; r < 4; ++r) {
        const int gm = bm0 + wm * 64 + i * 16 + rquad * 4 + r;  // = s*64 + b
        const int bb = gm & 63;
        float p = 0.f;
#pragma unroll
        for (int j = 0; j < 4; ++j) {
          const float u = Ubias[bb * 2048 + bn0 + wn * 64 + j * 16 + colb];
          p += tanh_fast(acc[i][j][r] + u) * w2f[j];
        }
        p += __shfl_xor(p, 1);
        p += __shfl_xor(p, 2);
        p += __shfl_xor(p, 4);
        p += __shfl_xor(p, 8);
        if (colb == 0) atomicAdd(outf + gm, p);
      }
    }
  } else {  // MODE 3: split-K partial, accumulate into pre-zeroed f32 buffer
    const float bsc = (blockIdx.z == 0) ? 1.f : 0.f;
#pragma unroll
    for (int i = 0; i < 4; ++i)
#pragma unroll
      for (int r = 0; r < 4; ++r) {
        const int gm = bm0 + wm * 64 + i * 16 + rquad * 4 + r;
        if (gm < M) {
#pragma unroll
          for (int j = 0; j < 4; ++j) {
            const int gn = bn0 + wn * 64 + j * 16 + colb;
            atomicAdd(outf + gm * 1024 + gn, acc[i][j][r] + bsc * bias[gn]);
          }
        }
      }
  }
}

// fused softmax + applied + acat + out_acc zeroing.
// grid (64 b, 16 h-chunks) x 256 thr; within a block the 512 s-values are
// split 8-way (sq = t>>5) and tree-reduced in LDS -> 1024 blocks (4/CU).
__global__ __launch_bounds__(256)
void applied_kernel(const uint16_t* __restrict__ encb, const float* __restrict__ dec,
                    const float* __restrict__ scores,
                    float* __restrict__ out_applied, uint16_t* __restrict__ acat,
                    float* __restrict__ out_acc) {
  const int b = blockIdx.x, chunk = blockIdx.y, t = threadIdx.x;
  const int wave = t >> 6, lane = t & 63;
  __shared__ float w[512];
  __shared__ float red[8];
  __shared__ float2 part2[256];
  // softmax over s for this b (each thread owns s=t and s=t+256)
  float v0 = scores[(size_t)t * 64 + b];
  float v1 = scores[(size_t)(t + 256) * 64 + b];
  float mx = fmaxf(v0, v1);
#pragma unroll
  for (int off = 32; off >= 1; off >>= 1) mx = fmaxf(mx, __shfl_xor(mx, off));
  if (lane == 0) red[wave] = mx;
  __syncthreads();
  mx = fmaxf(fmaxf(red[0], red[1]), fmaxf(red[2], red[3]));
  const float e0 = __expf(v0 - mx), e1 = __expf(v1 - mx);
  float sum = e0 + e1;
#pragma unroll
  for (int off = 32; off >= 1; off >>= 1) sum += __shfl_xor(sum, off);
  if (lane == 0) red[4 + wave] = sum;
  __syncthreads();
  sum = (red[4] + red[5]) + (red[6] + red[7]);
  const float inv = 1.f / sum;
  w[t] = e0 * inv;
  w[t + 256] = e1 * inv;
  __syncthreads();
  // applied: thread (hp, sq) sums s in [sq*64, sq*64+64) for h-pair hp
  const int hp = t & 31, sq = t >> 5;
  const int h = chunk * 64 + hp * 2;
  const uint32_t* base = (const uint32_t*)encb + (size_t)b * 512 + (h >> 1);
  float a0 = 0.f, a1 = 0.f;
#pragma unroll 8
  for (int s = sq * 64; s < sq * 64 + 64; ++s) {
    const uint32_t p = base[(size_t)s * 32768];
    a0 += w[s] * bf2f((uint16_t)(p & 0xffffu));
    a1 += w[s] * bf2f((uint16_t)(p >> 16));
  }
  part2[t] = make_float2(a0, a1);
  __syncthreads();
  if (t < 32) {
    a0 = 0.f; a1 = 0.f;
#pragma unroll
    for (int k = 0; k < 8; ++k) {
      const float2 pp = part2[t + 32 * k];
      a0 += pp.x; a1 += pp.y;
    }
    *(float2*)(out_applied + (size_t)b * 1024 + h) = make_float2(a0, a1);
    *(uint32_t*)(acat + (size_t)b * 2048 + 1024 + h) = pk2(a0, a1);
    *(uint32_t*)(acat + (size_t)b * 2048 + h) =
        pk2(dec[(size_t)b * 1024 + h], dec[(size_t)b * 1024 + h + 1]);
    *(float2*)(out_acc + (size_t)b * 1024 + h) = make_float2(0.f, 0.f);
  }
}

// out = tanh(out_acc), 16384 float4s: 64 blocks x 256.
__global__ __launch_bounds__(256)
void tanh_kernel(const float* __restrict__ acc, float* __restrict__ outp) {
  const int i = blockIdx.x * 256 + threadIdx.x;
  float4 v = ((const float4*)acc)[i];
  v.x = tanh_fast(v.x); v.y = tanh_fast(v.y);
  v.z = tanh_fast(v.z); v.w = tanh_fast(v.w);
  ((float4*)outp)[i] = v;
}

extern "C" void kernel_launch(void* const* d_in, const int* in_sizes, int n_in,
                              void* d_out, int out_size, void* d_ws, size_t ws_size,
                              hipStream_t stream) {
  const float* hidden  = (const float*)d_in[0];
  const float* dec     = (const float*)d_in[1];
  const float* enc     = (const float*)d_in[2];
  const float* W_attn  = (const float*)d_in[3];
  const float* b_attn  = (const float*)d_in[4];
  const float* W_attn2 = (const float*)d_in[5];
  const float* W_comb  = (const float*)d_in[7];
  const float* b_comb  = (const float*)d_in[8];
  float* outp = (float*)d_out;                 // [out 65536 | applied 65536] f32

  char* ws = (char*)d_ws;
  float*    scores = (float*)(ws + 0);             // 128 KB
  float*    U      = (float*)(ws + 131072);        // 512 KB (dead after mode-1)
  float*    out_acc= (float*)(ws + 131072);        // 256 KB, reuses U space
  uint16_t* acat   = (uint16_t*)(ws + 655360);     // 256 KB
  uint16_t* enc_bf = (uint16_t*)(ws + 1048576);    // 64 MB
  uint16_t* Wa_bf  = (uint16_t*)(ws + 68157440);   // 4 MB  [2048,1024]
  uint16_t* Wc_bf  = (uint16_t*)(ws + 72351744);   // 4 MB  [1024,2048]

  init_kernel<<<128, 256, 0, stream>>>(scores, U, b_attn);
  cvt_all_kernel<<<4608, 256, 0, stream>>>(enc, W_attn, W_comb, enc_bf, Wa_bf, Wc_bf);
  gemm_u_kernel<<<dim3(16, 4), 256, 0, stream>>>(hidden, W_attn, U);
  gemm_bf_kernel<1><<<dim3(256, 16), 256, 0, stream>>>(
      enc_bf, 1024, Wa_bf, 1024, 32768, 1024, scores, U, W_attn2);
  applied_kernel<<<dim3(64, 16), 256, 0, stream>>>(enc_bf, dec, scores,
                                                   outp + 65536, acat, out_acc);
  gemm_bf_kernel<3><<<dim3(1, 8, 4), 256, 0, stream>>>(
      acat, 2048, Wc_bf, 2048, 64, 2048, out_acc, nullptr, b_comb);
  tanh_kernel<<<64, 256, 0, stream>>>(out_acc, outp);
}

// Round 3
// 456.911 us; speedup vs baseline: 1.0611x; 1.0611x over previous
//
#include <hip/hip_runtime.h>
#include <stdint.h>

// AttentionModule: S=512, B=64, H=1024. Inputs f32, output f32.
// R11: gemm_bf with XCD-chunked A-panel-sharing grid (16 consecutive
//      same-XCD blocks share one 256KB A-panel in L2 -> staging loads hit
//      L2, depth-2 prefetch now covers latency), tri-buffer + XOR swizzle
//      kept, NT templated + fully unrolled (imm-offset addressing, no
//      runtime buffer rotation), clean drained tail (no redundant loads),
//      init fused into cvt_all.
//   cvt_all: enc/Wa_right/Wc -> bf16 + scores=0 + U=b_attn (one launch)
//   gemm_u: split-K(4) atomicAdd into U
//   mode-1: scores += sum_j tanh(enc@Wa_r.T + U)*W_attn2
//   applied: fused softmax + weighted sum + acat build + zero out_acc
//   mode-3: out_acc += acat @ Wc.T (+ b_comb on z==0), split-K(4)
//   tanh:   out = tanh(out_acc)

typedef __attribute__((ext_vector_type(8))) short bf16x8;
typedef __attribute__((ext_vector_type(4))) float f32x4;

__device__ __forceinline__ float bf2f(uint16_t u) {
  return __uint_as_float(((uint32_t)u) << 16);
}
__device__ __forceinline__ uint16_t f2bf(float x) {
  uint32_t u = __float_as_uint(x);
  u += 0x7fffu + ((u >> 16) & 1u);   // RNE
  return (uint16_t)(u >> 16);
}
__device__ __forceinline__ uint32_t pk2(float a, float b) {
  return (uint32_t)f2bf(a) | ((uint32_t)f2bf(b) << 16);
}
__device__ __forceinline__ uint4 cvt8(const float* __restrict__ p) {
  const float4 a = *(const float4*)p;
  const float4 b = *(const float4*)(p + 4);
  uint4 r;
  r.x = pk2(a.x, a.y); r.y = pk2(a.z, a.w);
  r.z = pk2(b.x, b.y); r.w = pk2(b.z, b.w);
  return r;
}
// tanh(x) = 1 - 2/(exp(2x)+1)
__device__ __forceinline__ float tanh_fast(float x) {
  const float e = __expf(2.f * x);
  return __builtin_fmaf(-2.f, __builtin_amdgcn_rcpf(e + 1.f), 1.f);
}
__device__ __forceinline__ void load16(const uint16_t* g, uint16_t* l) {
  __builtin_amdgcn_global_load_lds(
      (const __attribute__((address_space(1))) void*)g,
      (__attribute__((address_space(3))) void*)l, 16, 0, 0);
}

// one-shot converts + init: enc (4194304 u4) | Wa right half (262144 u4) |
// Wc (262144 u4); first 32768 threads also zero scores and prefill U=bias.
__global__ __launch_bounds__(256)
void cvt_all_kernel(const float* __restrict__ enc, const float* __restrict__ Wa,
                    const float* __restrict__ Wc,
                    uint16_t* __restrict__ enc_bf, uint16_t* __restrict__ Wa_bf,
                    uint16_t* __restrict__ Wc_bf,
                    float* __restrict__ scores, float* __restrict__ U,
                    const float* __restrict__ ba) {
  const int tid0 = blockIdx.x * 256 + threadIdx.x;
  if (tid0 < 32768) {
    scores[tid0] = 0.f;
#pragma unroll
    for (int k = 0; k < 4; ++k) {
      const int i = tid0 * 4 + k;
      U[i] = ba[i & 2047];
    }
  }
  const int stride = gridDim.x * 256;
  for (int idx = tid0; idx < 4718592; idx += stride) {
    if (idx < 4194304) {
      ((uint4*)enc_bf)[idx] = cvt8(enc + (size_t)idx * 8);
    } else if (idx < 4456448) {
      const int k = idx - 4194304;
      const int j = k >> 7, c8 = k & 127;
      ((uint4*)Wa_bf)[k] = cvt8(Wa + (size_t)j * 2048 + 1024 + c8 * 8);
    } else {
      const int k = idx - 4456448;
      ((uint4*)Wc_bf)[k] = cvt8(Wc + (size_t)k * 8);
    }
  }
}

// split-K U-GEMM: U[b,j] += hidden[b,:]@W_attn[j,:1024].T over K-slice.
// grid (16 n-blocks, 4 k-splits); U prefilled with bias by cvt_all.
__global__ __launch_bounds__(256)
void gemm_u_kernel(const float* __restrict__ A, const float* __restrict__ B32,
                   float* __restrict__ U) {
  __shared__ __align__(16) uint16_t sA[128 * 32];
  __shared__ __align__(16) uint16_t sB[128 * 32];
  const int t = threadIdx.x, lane = t & 63, wave = t >> 6;
  const int wm = wave >> 1, wn = wave & 1;
  const int bn0 = blockIdx.x * 128;
  const int kbase = blockIdx.y * 256;
  const int srow = t >> 2, scol = (t & 3) * 8;
  const int ar0 = min(srow, 63), ar1 = min(64 + srow, 63);
  f32x4 acc[4][4];
#pragma unroll
  for (int i = 0; i < 4; ++i)
#pragma unroll
    for (int j = 0; j < 4; ++j) acc[i][j] = (f32x4){0.f, 0.f, 0.f, 0.f};
  const int mrow = wm * 64 + (lane & 15);
  const int nrow = wn * 64 + (lane & 15);
  const int kq = (lane >> 4) * 8;
  for (int kk = 0; kk < 8; ++kk) {
    const int k0 = kbase + (kk << 5);
    const uint4 va0 = cvt8(A + (size_t)ar0 * 1024 + scol + k0);
    const uint4 va1 = cvt8(A + (size_t)ar1 * 1024 + scol + k0);
    const uint4 vb0 = cvt8(B32 + (size_t)(bn0 + srow) * 2048 + scol + k0);
    const uint4 vb1 = cvt8(B32 + (size_t)(bn0 + 64 + srow) * 2048 + scol + k0);
    __syncthreads();
    *(uint4*)&sA[t * 8] = va0;
    *(uint4*)&sA[2048 + t * 8] = va1;
    *(uint4*)&sB[t * 8] = vb0;
    *(uint4*)&sB[2048 + t * 8] = vb1;
    __syncthreads();
    bf16x8 af[4], bfr[4];
#pragma unroll
    for (int i = 0; i < 4; ++i) af[i] = *(const bf16x8*)&sA[(mrow + i * 16) * 32 + kq];
#pragma unroll
    for (int j = 0; j < 4; ++j) bfr[j] = *(const bf16x8*)&sB[(nrow + j * 16) * 32 + kq];
#pragma unroll
    for (int i = 0; i < 4; ++i)
#pragma unroll
      for (int j = 0; j < 4; ++j)
        acc[i][j] = __builtin_amdgcn_mfma_f32_16x16x32_bf16(af[i], bfr[j], acc[i][j], 0, 0, 0);
  }
  const int colb = lane & 15, rquad = lane >> 4;
#pragma unroll
  for (int i = 0; i < 4; ++i)
#pragma unroll
    for (int r = 0; r < 4; ++r) {
      const int gm = wm * 64 + i * 16 + rquad * 4 + r;
      if (gm < 64) {
#pragma unroll
        for (int j = 0; j < 4; ++j) {
          const int gn = bn0 + wn * 64 + j * 16 + colb;
          atomicAdd(&U[gm * 2048 + gn], acc[i][j][r]);
        }
      }
    }
}

// ---- bf16 GEMM, tri-buffered global_load_lds, prefetch depth 2, counted
// vmcnt(4)+lgkmcnt(0) raw barriers. NT = number of K-tiles (compile-time,
// fully unrolled: all buffer indices / LDS offsets / stage offsets are
// immediates). XOR-swizzled LDS (conflict-free), clean drained tail.
// MODE 1: grid 4096 1-D, XCD-chunked decode: xcd=wid&7 owns m-panels
//         [32*xcd,32*xcd+32) x all 16 n; n-fast within -> 16 consecutive
//         same-XCD blocks share one A-panel (L2-hit staging).
//         epilogue: atomicAdd(scores[gm], sum_n tanh(acc+U[gm&63,gn])*w2[gn])
// MODE 3: grid (1, N/128, Ksplit), K-slice = NT*32 per z.
template <int MODE, int NT>
__global__ __launch_bounds__(256)
void gemm_bf_kernel(const uint16_t* __restrict__ A, int lda,
                    const uint16_t* __restrict__ Bm, int ldb,
                    int M, float* __restrict__ outf,
                    const float* __restrict__ Ubias,
                    const float* __restrict__ bias) {
  __shared__ __align__(16) uint16_t lds[3][2][4096];  // 48 KB tri-buffer

  const int t = threadIdx.x, lane = t & 63, wave = t >> 6;
  const int wm = wave >> 1, wn = wave & 1;
  int bm0, bn0, kbase;
  if (MODE == 1) {
    const int wid = blockIdx.x;
    const int xcd = wid & 7, q = wid >> 3;
    bm0 = (xcd * 32 + (q >> 4)) * 128;
    bn0 = (q & 15) * 128;
    kbase = 0;
  } else {
    bm0 = 0;
    bn0 = blockIdx.y * 128;
    kbase = blockIdx.z * (NT * 32);
  }

  // staging map: operand tile = 512 slots of 16B; thread covers slots
  // s = q*256 + t. slot -> r=s>>2, kc=s&3, global chunk kc^((r>>1)&3).
  const uint16_t* gpA[2];
  const uint16_t* gpB[2];
  int sb[2];
#pragma unroll
  for (int q = 0; q < 2; ++q) {
    const int s = q * 256 + t;
    const int r = s >> 2, kc = s & 3;
    const int g = kc ^ ((r >> 1) & 3);
    gpA[q] = A + (size_t)min(bm0 + r, M - 1) * lda + kbase + g * 8;
    gpB[q] = Bm + (size_t)(bn0 + r) * ldb + kbase + g * 8;
    sb[q] = (q * 256 + wave * 64) * 8;   // wave-uniform LDS base (elems)
  }

  f32x4 acc[4][4];
#pragma unroll
  for (int i = 0; i < 4; ++i)
#pragma unroll
    for (int j = 0; j < 4; ++j) acc[i][j] = (f32x4){0.f, 0.f, 0.f, 0.f};

  // fragment read offsets: row = wX*64 + i*16 + (lane&15), stored col =
  // kq ^ swz with swz = ((lane>>1)&3)<<3 (row bits 1-2, constant over i).
  const int swz = ((lane >> 1) & 3) << 3;
  const int kq = ((lane >> 4) * 8) ^ swz;
  const int aoff = (wm * 64 + (lane & 15)) * 32 + kq;
  const int boff = (wn * 64 + (lane & 15)) * 32 + kq;

  // prologue: stage tiles 0,1 into bufs 0,1; drain tile0 (tile1 in flight)
#pragma unroll
  for (int q = 0; q < 2; ++q) {
    load16(gpA[q], &lds[0][0][sb[q]]);
    load16(gpB[q], &lds[0][1][sb[q]]);
  }
#pragma unroll
  for (int q = 0; q < 2; ++q) {
    load16(gpA[q] + 32, &lds[1][0][sb[q]]);
    load16(gpB[q] + 32, &lds[1][1][sb[q]]);
  }
  asm volatile("s_waitcnt vmcnt(4)" ::: "memory");
  __builtin_amdgcn_s_barrier();

#pragma unroll
  for (int kt = 0; kt < NT; ++kt) {
    const int bufc = kt % 3;
    if (kt + 2 < NT) {
      const int nb = (kt + 2) % 3;
      const int kpre = (kt + 2) * 32;
#pragma unroll
      for (int q = 0; q < 2; ++q) {
        load16(gpA[q] + kpre, &lds[nb][0][sb[q]]);
        load16(gpB[q] + kpre, &lds[nb][1][sb[q]]);
      }
    }
    const uint16_t* sA = lds[bufc][0];
    const uint16_t* sB = lds[bufc][1];
    bf16x8 af[4], bfr[4];
#pragma unroll
    for (int i = 0; i < 4; ++i) af[i] = *(const bf16x8*)&sA[aoff + i * 512];
#pragma unroll
    for (int j = 0; j < 4; ++j) bfr[j] = *(const bf16x8*)&sB[boff + j * 512];
#pragma unroll
    for (int i = 0; i < 4; ++i)
#pragma unroll
      for (int j = 0; j < 4; ++j)
        acc[i][j] = __builtin_amdgcn_mfma_f32_16x16x32_bf16(af[i], bfr[j], acc[i][j], 0, 0, 0);
    // before next tile: its loads must be drained; keep deeper prefetch in
    // flight (vmcnt(4)) in steady state; full drain entering the tail.
    if (kt + 2 < NT) {
      asm volatile("s_waitcnt vmcnt(4) lgkmcnt(0)" ::: "memory");
      __builtin_amdgcn_s_barrier();
    } else if (kt + 1 < NT) {
      asm volatile("s_waitcnt vmcnt(0) lgkmcnt(0)" ::: "memory");
      __builtin_amdgcn_s_barrier();
    }
  }

  const int colb = lane & 15, rquad = lane >> 4;
  if (MODE == 1) {
    float w2f[4];
#pragma unroll
    for (int j = 0; j < 4; ++j) w2f[j] = bias[bn0 + wn * 64 + j * 16 + colb];
#pragma unroll
    for (int i = 0; i < 4; ++i) {
#pragma unroll
      for (int r = 0; r < 4; ++r) {
        const int gm = bm0 + wm * 64 + i * 16 + rquad * 4 + r;  // = s*64 + b
        const int bb = gm & 63;
        float p = 0.f;
#pragma unroll
        for (int j = 0; j < 4; ++j) {
          const float u = Ubias[bb * 2048 + bn0 + wn * 64 + j * 16 + colb];
          p += tanh_fast(acc[i][j][r] + u) * w2f[j];
        }
        p += __shfl_xor(p, 1);
        p += __shfl_xor(p, 2);
        p += __shfl_xor(p, 4);
        p += __shfl_xor(p, 8);
        if (colb == 0) atomicAdd(outf + gm, p);
      }
    }
  } else {  // MODE 3: split-K partial, accumulate into pre-zeroed f32 buffer
    const float bsc = (blockIdx.z == 0) ? 1.f : 0.f;
#pragma unroll
    for (int i = 0; i < 4; ++i)
#pragma unroll
      for (int r = 0; r < 4; ++r) {
        const int gm = bm0 + wm * 64 + i * 16 + rquad * 4 + r;
        if (gm < M) {
#pragma unroll
          for (int j = 0; j < 4; ++j) {
            const int gn = bn0 + wn * 64 + j * 16 + colb;
            atomicAdd(outf + gm * 1024 + gn, acc[i][j][r] + bsc * bias[gn]);
          }
        }
      }
  }
}

// fused softmax + applied + acat + out_acc zeroing.
// grid (64 b, 16 h-chunks) x 256 thr; within a block the 512 s-values are
// split 8-way (sq = t>>5) and tree-reduced in LDS -> 1024 blocks (4/CU).
__global__ __launch_bounds__(256)
void applied_kernel(const uint16_t* __restrict__ encb, const float* __restrict__ dec,
                    const float* __restrict__ scores,
                    float* __restrict__ out_applied, uint16_t* __restrict__ acat,
                    float* __restrict__ out_acc) {
  const int b = blockIdx.x, chunk = blockIdx.y, t = threadIdx.x;
  const int wave = t >> 6, lane = t & 63;
  __shared__ float w[512];
  __shared__ float red[8];
  __shared__ float2 part2[256];
  // softmax over s for this b (each thread owns s=t and s=t+256)
  float v0 = scores[(size_t)t * 64 + b];
  float v1 = scores[(size_t)(t + 256) * 64 + b];
  float mx = fmaxf(v0, v1);
#pragma unroll
  for (int off = 32; off >= 1; off >>= 1) mx = fmaxf(mx, __shfl_xor(mx, off));
  if (lane == 0) red[wave] = mx;
  __syncthreads();
  mx = fmaxf(fmaxf(red[0], red[1]), fmaxf(red[2], red[3]));
  const float e0 = __expf(v0 - mx), e1 = __expf(v1 - mx);
  float sum = e0 + e1;
#pragma unroll
  for (int off = 32; off >= 1; off >>= 1) sum += __shfl_xor(sum, off);
  if (lane == 0) red[4 + wave] = sum;
  __syncthreads();
  sum = (red[4] + red[5]) + (red[6] + red[7]);
  const float inv = 1.f / sum;
  w[t] = e0 * inv;
  w[t + 256] = e1 * inv;
  __syncthreads();
  // applied: thread (hp, sq) sums s in [sq*64, sq*64+64) for h-pair hp
  const int hp = t & 31, sq = t >> 5;
  const int h = chunk * 64 + hp * 2;
  const uint32_t* base = (const uint32_t*)encb + (size_t)b * 512 + (h >> 1);
  float a0 = 0.f, a1 = 0.f;
#pragma unroll 8
  for (int s = sq * 64; s < sq * 64 + 64; ++s) {
    const uint32_t p = base[(size_t)s * 32768];
    a0 += w[s] * bf2f((uint16_t)(p & 0xffffu));
    a1 += w[s] * bf2f((uint16_t)(p >> 16));
  }
  part2[t] = make_float2(a0, a1);
  __syncthreads();
  if (t < 32) {
    a0 = 0.f; a1 = 0.f;
#pragma unroll
    for (int k = 0; k < 8; ++k) {
      const float2 pp = part2[t + 32 * k];
      a0 += pp.x; a1 += pp.y;
    }
    *(float2*)(out_applied + (size_t)b * 1024 + h) = make_float2(a0, a1);
    *(uint32_t*)(acat + (size_t)b * 2048 + 1024 + h) = pk2(a0, a1);
    *(uint32_t*)(acat + (size_t)b * 2048 + h) =
        pk2(dec[(size_t)b * 1024 + h], dec[(size_t)b * 1024 + h + 1]);
    *(float2*)(out_acc + (size_t)b * 1024 + h) = make_float2(0.f, 0.f);
  }
}

// out = tanh(out_acc), 16384 float4s: 64 blocks x 256.
__global__ __launch_bounds__(256)
void tanh_kernel(const float* __restrict__ acc, float* __restrict__ outp) {
  const int i = blockIdx.x * 256 + threadIdx.x;
  float4 v = ((const float4*)acc)[i];
  v.x = tanh_fast(v.x); v.y = tanh_fast(v.y);
  v.z = tanh_fast(v.z); v.w = tanh_fast(v.w);
  ((float4*)outp)[i] = v;
}

extern "C" void kernel_launch(void* const* d_in, const int* in_sizes, int n_in,
                              void* d_out, int out_size, void* d_ws, size_t ws_size,
                              hipStream_t stream) {
  const float* hidden  = (const float*)d_in[0];
  const float* dec     = (const float*)d_in[1];
  const float* enc     = (const float*)d_in[2];
  const float* W_attn  = (const float*)d_in[3];
  const float* b_attn  = (const float*)d_in[4];
  const float* W_attn2 = (const float*)d_in[5];
  const float* W_comb  = (const float*)d_in[7];
  const float* b_comb  = (const float*)d_in[8];
  float* outp = (float*)d_out;                 // [out 65536 | applied 65536] f32

  char* ws = (char*)d_ws;
  float*    scores = (float*)(ws + 0);             // 128 KB
  float*    U      = (float*)(ws + 131072);        // 512 KB (dead after mode-1)
  float*    out_acc= (float*)(ws + 131072);        // 256 KB, reuses U space
  uint16_t* acat   = (uint16_t*)(ws + 655360);     // 256 KB
  uint16_t* enc_bf = (uint16_t*)(ws + 1048576);    // 64 MB
  uint16_t* Wa_bf  = (uint16_t*)(ws + 68157440);   // 4 MB  [2048,1024]
  uint16_t* Wc_bf  = (uint16_t*)(ws + 72351744);   // 4 MB  [1024,2048]

  cvt_all_kernel<<<4608, 256, 0, stream>>>(enc, W_attn, W_comb, enc_bf, Wa_bf,
                                           Wc_bf, scores, U, b_attn);
  gemm_u_kernel<<<dim3(16, 4), 256, 0, stream>>>(hidden, W_attn, U);
  gemm_bf_kernel<1, 32><<<4096, 256, 0, stream>>>(
      enc_bf, 1024, Wa_bf, 1024, 32768, scores, U, W_attn2);
  applied_kernel<<<dim3(64, 16), 256, 0, stream>>>(enc_bf, dec, scores,
                                                   outp + 65536, acat, out_acc);
  gemm_bf_kernel<3, 16><<<dim3(1, 8, 4), 256, 0, stream>>>(
      acat, 2048, Wc_bf, 2048, 64, out_acc, nullptr, b_comb);
  tanh_kernel<<<64, 256, 0, stream>>>(out_acc, outp);
}

// Round 4
// 451.768 us; speedup vs baseline: 1.0731x; 1.0114x over previous
//
#include <hip/hip_runtime.h>
#include <stdint.h>

// AttentionModule: S=512, B=64, H=1024. Inputs f32, output f32.
// R12: gemm1 re-tiled to 256x256 block / 8 waves / 128x64 wave-tile
//      (FLOP per LDS-byte 32 -> 42.7, halves staging per FLOP). Tri-buffer
//      depth-2 prefetch + counted vmcnt(4) + XOR swizzle + full unroll kept
//      from R11 (proven). XCD-chunked n-fast grid: 8 blocks share A-panel.
//   cvt_all: enc/Wa_right/Wc -> bf16 + scores=0 + U=b_attn (one launch)
//   gemm_u: split-K(4) atomicAdd into U
//   gemm_score (new): scores += sum_j tanh(enc@Wa_r.T + U)*W_attn2
//   applied: fused softmax + weighted sum + acat build + zero out_acc
//   gemm_bf<3>: out_acc += acat @ Wc.T (+ b_comb on z==0), split-K(4)
//   tanh:   out = tanh(out_acc)

typedef __attribute__((ext_vector_type(8))) short bf16x8;
typedef __attribute__((ext_vector_type(4))) float f32x4;

__device__ __forceinline__ float bf2f(uint16_t u) {
  return __uint_as_float(((uint32_t)u) << 16);
}
__device__ __forceinline__ uint16_t f2bf(float x) {
  uint32_t u = __float_as_uint(x);
  u += 0x7fffu + ((u >> 16) & 1u);   // RNE
  return (uint16_t)(u >> 16);
}
__device__ __forceinline__ uint32_t pk2(float a, float b) {
  return (uint32_t)f2bf(a) | ((uint32_t)f2bf(b) << 16);
}
__device__ __forceinline__ uint4 cvt8(const float* __restrict__ p) {
  const float4 a = *(const float4*)p;
  const float4 b = *(const float4*)(p + 4);
  uint4 r;
  r.x = pk2(a.x, a.y); r.y = pk2(a.z, a.w);
  r.z = pk2(b.x, b.y); r.w = pk2(b.z, b.w);
  return r;
}
// tanh(x) = 1 - 2/(exp(2x)+1)
__device__ __forceinline__ float tanh_fast(float x) {
  const float e = __expf(2.f * x);
  return __builtin_fmaf(-2.f, __builtin_amdgcn_rcpf(e + 1.f), 1.f);
}
__device__ __forceinline__ void load16(const uint16_t* g, uint16_t* l) {
  __builtin_amdgcn_global_load_lds(
      (const __attribute__((address_space(1))) void*)g,
      (__attribute__((address_space(3))) void*)l, 16, 0, 0);
}

// one-shot converts + init: enc (4194304 u4) | Wa right half (262144 u4) |
// Wc (262144 u4); first 32768 threads also zero scores and prefill U=bias.
__global__ __launch_bounds__(256)
void cvt_all_kernel(const float* __restrict__ enc, const float* __restrict__ Wa,
                    const float* __restrict__ Wc,
                    uint16_t* __restrict__ enc_bf, uint16_t* __restrict__ Wa_bf,
                    uint16_t* __restrict__ Wc_bf,
                    float* __restrict__ scores, float* __restrict__ U,
                    const float* __restrict__ ba) {
  const int tid0 = blockIdx.x * 256 + threadIdx.x;
  if (tid0 < 32768) {
    scores[tid0] = 0.f;
#pragma unroll
    for (int k = 0; k < 4; ++k) {
      const int i = tid0 * 4 + k;
      U[i] = ba[i & 2047];
    }
  }
  const int stride = gridDim.x * 256;
  for (int idx = tid0; idx < 4718592; idx += stride) {
    if (idx < 4194304) {
      ((uint4*)enc_bf)[idx] = cvt8(enc + (size_t)idx * 8);
    } else if (idx < 4456448) {
      const int k = idx - 4194304;
      const int j = k >> 7, c8 = k & 127;
      ((uint4*)Wa_bf)[k] = cvt8(Wa + (size_t)j * 2048 + 1024 + c8 * 8);
    } else {
      const int k = idx - 4456448;
      ((uint4*)Wc_bf)[k] = cvt8(Wc + (size_t)k * 8);
    }
  }
}

// split-K U-GEMM: U[b,j] += hidden[b,:]@W_attn[j,:1024].T over K-slice.
// grid (16 n-blocks, 4 k-splits); U prefilled with bias by cvt_all.
__global__ __launch_bounds__(256)
void gemm_u_kernel(const float* __restrict__ A, const float* __restrict__ B32,
                   float* __restrict__ U) {
  __shared__ __align__(16) uint16_t sA[128 * 32];
  __shared__ __align__(16) uint16_t sB[128 * 32];
  const int t = threadIdx.x, lane = t & 63, wave = t >> 6;
  const int wm = wave >> 1, wn = wave & 1;
  const int bn0 = blockIdx.x * 128;
  const int kbase = blockIdx.y * 256;
  const int srow = t >> 2, scol = (t & 3) * 8;
  const int ar0 = min(srow, 63), ar1 = min(64 + srow, 63);
  f32x4 acc[4][4];
#pragma unroll
  for (int i = 0; i < 4; ++i)
#pragma unroll
    for (int j = 0; j < 4; ++j) acc[i][j] = (f32x4){0.f, 0.f, 0.f, 0.f};
  const int mrow = wm * 64 + (lane & 15);
  const int nrow = wn * 64 + (lane & 15);
  const int kq = (lane >> 4) * 8;
  for (int kk = 0; kk < 8; ++kk) {
    const int k0 = kbase + (kk << 5);
    const uint4 va0 = cvt8(A + (size_t)ar0 * 1024 + scol + k0);
    const uint4 va1 = cvt8(A + (size_t)ar1 * 1024 + scol + k0);
    const uint4 vb0 = cvt8(B32 + (size_t)(bn0 + srow) * 2048 + scol + k0);
    const uint4 vb1 = cvt8(B32 + (size_t)(bn0 + 64 + srow) * 2048 + scol + k0);
    __syncthreads();
    *(uint4*)&sA[t * 8] = va0;
    *(uint4*)&sA[2048 + t * 8] = va1;
    *(uint4*)&sB[t * 8] = vb0;
    *(uint4*)&sB[2048 + t * 8] = vb1;
    __syncthreads();
    bf16x8 af[4], bfr[4];
#pragma unroll
    for (int i = 0; i < 4; ++i) af[i] = *(const bf16x8*)&sA[(mrow + i * 16) * 32 + kq];
#pragma unroll
    for (int j = 0; j < 4; ++j) bfr[j] = *(const bf16x8*)&sB[(nrow + j * 16) * 32 + kq];
#pragma unroll
    for (int i = 0; i < 4; ++i)
#pragma unroll
      for (int j = 0; j < 4; ++j)
        acc[i][j] = __builtin_amdgcn_mfma_f32_16x16x32_bf16(af[i], bfr[j], acc[i][j], 0, 0, 0);
  }
  const int colb = lane & 15, rquad = lane >> 4;
#pragma unroll
  for (int i = 0; i < 4; ++i)
#pragma unroll
    for (int r = 0; r < 4; ++r) {
      const int gm = wm * 64 + i * 16 + rquad * 4 + r;
      if (gm < 64) {
#pragma unroll
        for (int j = 0; j < 4; ++j) {
          const int gn = bn0 + wn * 64 + j * 16 + colb;
          atomicAdd(&U[gm * 2048 + gn], acc[i][j][r]);
        }
      }
    }
}

// ---- gemm1 replacement: 256x256 tile, 8 waves (512 thr), wave-tile 128x64.
// Tri-buffered global_load_lds, prefetch depth 2, vmcnt(4)+lgkmcnt(0) raw
// barriers, XOR-swizzled LDS, NT=32 fully unrolled.
// Grid 1024 1-D XCD-chunked: xcd=wid&7 owns m-panels [16*xcd,16*xcd+16),
// n-fast within -> 8 consecutive same-XCD blocks share one 512KB A-panel.
// Epilogue: atomicAdd(scores[gm], sum_n tanh(acc + U[gm&63,gn]) * w2[gn]).
__global__ __launch_bounds__(512, 2)
void gemm_score_kernel(const uint16_t* __restrict__ A,
                       const uint16_t* __restrict__ Bm,
                       float* __restrict__ outf,
                       const float* __restrict__ Ubias,
                       const float* __restrict__ bias) {
  __shared__ __align__(16) uint16_t lds[3][2][8192];  // 96 KB tri-buffer

  const int t = threadIdx.x, lane = t & 63, wave = t >> 6;
  const int wm = wave >> 2, wn = wave & 3;   // 2m x 4n wave grid
  const int wid = blockIdx.x;
  const int xcd = wid & 7, q = wid >> 3;     // q in [0,128)
  const int bm0 = (xcd * 16 + (q >> 3)) * 256;
  const int bn0 = (q & 7) * 256;

  // staging map: operand tile = 1024 slots of 16B; thread covers slots
  // s = qq*512 + t. slot -> r=s>>2, kc=s&3, global chunk kc^((r>>1)&3).
  const uint16_t* gpA[2];
  const uint16_t* gpB[2];
  int sb[2];
#pragma unroll
  for (int qq = 0; qq < 2; ++qq) {
    const int s = qq * 512 + t;
    const int r = s >> 2, kc = s & 3;
    const int g = kc ^ ((r >> 1) & 3);
    gpA[qq] = A + (size_t)(bm0 + r) * 1024 + g * 8;
    gpB[qq] = Bm + (size_t)(bn0 + r) * 1024 + g * 8;
    sb[qq] = (qq * 512 + wave * 64) * 8;   // wave-uniform LDS base (elems)
  }

  f32x4 acc[8][4];
#pragma unroll
  for (int i = 0; i < 8; ++i)
#pragma unroll
    for (int j = 0; j < 4; ++j) acc[i][j] = (f32x4){0.f, 0.f, 0.f, 0.f};

  // fragment read offsets: row = wm*128 + i*16 + (lane&15), stored col =
  // kq ^ swz with swz = ((lane>>1)&3)<<3 (row bits 1-2, constant over i).
  const int swz = ((lane >> 1) & 3) << 3;
  const int kq = ((lane >> 4) * 8) ^ swz;
  const int aoff = (wm * 128 + (lane & 15)) * 32 + kq;
  const int boff = (wn * 64 + (lane & 15)) * 32 + kq;

  // prologue: stage tiles 0,1 into bufs 0,1; drain tile0 (tile1 in flight)
#pragma unroll
  for (int qq = 0; qq < 2; ++qq) {
    load16(gpA[qq], &lds[0][0][sb[qq]]);
    load16(gpB[qq], &lds[0][1][sb[qq]]);
  }
#pragma unroll
  for (int qq = 0; qq < 2; ++qq) {
    load16(gpA[qq] + 32, &lds[1][0][sb[qq]]);
    load16(gpB[qq] + 32, &lds[1][1][sb[qq]]);
  }
  asm volatile("s_waitcnt vmcnt(4)" ::: "memory");
  __builtin_amdgcn_s_barrier();

  constexpr int NT = 32;
#pragma unroll
  for (int kt = 0; kt < NT; ++kt) {
    const int bufc = kt % 3;
    if (kt + 2 < NT) {
      const int nb = (kt + 2) % 3;
      const int kpre = (kt + 2) * 32;
#pragma unroll
      for (int qq = 0; qq < 2; ++qq) {
        load16(gpA[qq] + kpre, &lds[nb][0][sb[qq]]);
        load16(gpB[qq] + kpre, &lds[nb][1][sb[qq]]);
      }
    }
    const uint16_t* sA = lds[bufc][0];
    const uint16_t* sB = lds[bufc][1];
    bf16x8 af[8], bfr[4];
#pragma unroll
    for (int i = 0; i < 8; ++i) af[i] = *(const bf16x8*)&sA[aoff + i * 512];
#pragma unroll
    for (int j = 0; j < 4; ++j) bfr[j] = *(const bf16x8*)&sB[boff + j * 512];
#pragma unroll
    for (int i = 0; i < 8; ++i)
#pragma unroll
      for (int j = 0; j < 4; ++j)
        acc[i][j] = __builtin_amdgcn_mfma_f32_16x16x32_bf16(af[i], bfr[j], acc[i][j], 0, 0, 0);
    // before next tile: its loads must be drained; keep deeper prefetch in
    // flight (vmcnt(4)) in steady state; full drain entering the tail.
    if (kt + 2 < NT) {
      asm volatile("s_waitcnt vmcnt(4) lgkmcnt(0)" ::: "memory");
      __builtin_amdgcn_s_barrier();
    } else if (kt + 1 < NT) {
      asm volatile("s_waitcnt vmcnt(0) lgkmcnt(0)" ::: "memory");
      __builtin_amdgcn_s_barrier();
    }
  }

  const int colb = lane & 15, rquad = lane >> 4;
  float w2f[4];
#pragma unroll
  for (int j = 0; j < 4; ++j) w2f[j] = bias[bn0 + wn * 64 + j * 16 + colb];
#pragma unroll
  for (int i = 0; i < 8; ++i) {
#pragma unroll
    for (int r = 0; r < 4; ++r) {
      const int gm = bm0 + wm * 128 + i * 16 + rquad * 4 + r;  // = s*64 + b
      const int bb = gm & 63;
      float p = 0.f;
#pragma unroll
      for (int j = 0; j < 4; ++j) {
        const float u = Ubias[bb * 2048 + bn0 + wn * 64 + j * 16 + colb];
        p += tanh_fast(acc[i][j][r] + u) * w2f[j];
      }
      p += __shfl_xor(p, 1);
      p += __shfl_xor(p, 2);
      p += __shfl_xor(p, 4);
      p += __shfl_xor(p, 8);
      if (colb == 0) atomicAdd(outf + gm, p);
    }
  }
}

// ---- small split-K GEMM for out = acat @ Wc.T (R11 structure, MODE-3 only).
// grid (1, N/128, Ksplit), K-slice = NT*32 per z. atomicAdd into pre-zeroed
// f32 accumulator (+ bias on z==0).
template <int NT>
__global__ __launch_bounds__(256)
void gemm_comb_kernel(const uint16_t* __restrict__ A, int lda,
                      const uint16_t* __restrict__ Bm, int ldb,
                      int M, float* __restrict__ outf,
                      const float* __restrict__ bias) {
  __shared__ __align__(16) uint16_t lds[3][2][4096];  // 48 KB tri-buffer

  const int t = threadIdx.x, lane = t & 63, wave = t >> 6;
  const int wm = wave >> 1, wn = wave & 1;
  const int bm0 = 0;
  const int bn0 = blockIdx.y * 128;
  const int kbase = blockIdx.z * (NT * 32);

  const uint16_t* gpA[2];
  const uint16_t* gpB[2];
  int sb[2];
#pragma unroll
  for (int q = 0; q < 2; ++q) {
    const int s = q * 256 + t;
    const int r = s >> 2, kc = s & 3;
    const int g = kc ^ ((r >> 1) & 3);
    gpA[q] = A + (size_t)min(bm0 + r, M - 1) * lda + kbase + g * 8;
    gpB[q] = Bm + (size_t)(bn0 + r) * ldb + kbase + g * 8;
    sb[q] = (q * 256 + wave * 64) * 8;
  }

  f32x4 acc[4][4];
#pragma unroll
  for (int i = 0; i < 4; ++i)
#pragma unroll
    for (int j = 0; j < 4; ++j) acc[i][j] = (f32x4){0.f, 0.f, 0.f, 0.f};

  const int swz = ((lane >> 1) & 3) << 3;
  const int kq = ((lane >> 4) * 8) ^ swz;
  const int aoff = (wm * 64 + (lane & 15)) * 32 + kq;
  const int boff = (wn * 64 + (lane & 15)) * 32 + kq;

#pragma unroll
  for (int q = 0; q < 2; ++q) {
    load16(gpA[q], &lds[0][0][sb[q]]);
    load16(gpB[q], &lds[0][1][sb[q]]);
  }
#pragma unroll
  for (int q = 0; q < 2; ++q) {
    load16(gpA[q] + 32, &lds[1][0][sb[q]]);
    load16(gpB[q] + 32, &lds[1][1][sb[q]]);
  }
  asm volatile("s_waitcnt vmcnt(4)" ::: "memory");
  __builtin_amdgcn_s_barrier();

#pragma unroll
  for (int kt = 0; kt < NT; ++kt) {
    const int bufc = kt % 3;
    if (kt + 2 < NT) {
      const int nb = (kt + 2) % 3;
      const int kpre = (kt + 2) * 32;
#pragma unroll
      for (int q = 0; q < 2; ++q) {
        load16(gpA[q] + kpre, &lds[nb][0][sb[q]]);
        load16(gpB[q] + kpre, &lds[nb][1][sb[q]]);
      }
    }
    const uint16_t* sA = lds[bufc][0];
    const uint16_t* sB = lds[bufc][1];
    bf16x8 af[4], bfr[4];
#pragma unroll
    for (int i = 0; i < 4; ++i) af[i] = *(const bf16x8*)&sA[aoff + i * 512];
#pragma unroll
    for (int j = 0; j < 4; ++j) bfr[j] = *(const bf16x8*)&sB[boff + j * 512];
#pragma unroll
    for (int i = 0; i < 4; ++i)
#pragma unroll
      for (int j = 0; j < 4; ++j)
        acc[i][j] = __builtin_amdgcn_mfma_f32_16x16x32_bf16(af[i], bfr[j], acc[i][j], 0, 0, 0);
    if (kt + 2 < NT) {
      asm volatile("s_waitcnt vmcnt(4) lgkmcnt(0)" ::: "memory");
      __builtin_amdgcn_s_barrier();
    } else if (kt + 1 < NT) {
      asm volatile("s_waitcnt vmcnt(0) lgkmcnt(0)" ::: "memory");
      __builtin_amdgcn_s_barrier();
    }
  }

  const int colb = lane & 15, rquad = lane >> 4;
  const float bsc = (blockIdx.z == 0) ? 1.f : 0.f;
#pragma unroll
  for (int i = 0; i < 4; ++i)
#pragma unroll
    for (int r = 0; r < 4; ++r) {
      const int gm = bm0 + wm * 64 + i * 16 + rquad * 4 + r;
      if (gm < M) {
#pragma unroll
        for (int j = 0; j < 4; ++j) {
          const int gn = bn0 + wn * 64 + j * 16 + colb;
          atomicAdd(outf + gm * 1024 + gn, acc[i][j][r] + bsc * bias[gn]);
        }
      }
    }
}

// fused softmax + applied + acat + out_acc zeroing.
// grid (64 b, 16 h-chunks) x 256 thr; within a block the 512 s-values are
// split 8-way (sq = t>>5) and tree-reduced in LDS -> 1024 blocks (4/CU).
__global__ __launch_bounds__(256)
void applied_kernel(const uint16_t* __restrict__ encb, const float* __restrict__ dec,
                    const float* __restrict__ scores,
                    float* __restrict__ out_applied, uint16_t* __restrict__ acat,
                    float* __restrict__ out_acc) {
  const int b = blockIdx.x, chunk = blockIdx.y, t = threadIdx.x;
  const int wave = t >> 6, lane = t & 63;
  __shared__ float w[512];
  __shared__ float red[8];
  __shared__ float2 part2[256];
  // softmax over s for this b (each thread owns s=t and s=t+256)
  float v0 = scores[(size_t)t * 64 + b];
  float v1 = scores[(size_t)(t + 256) * 64 + b];
  float mx = fmaxf(v0, v1);
#pragma unroll
  for (int off = 32; off >= 1; off >>= 1) mx = fmaxf(mx, __shfl_xor(mx, off));
  if (lane == 0) red[wave] = mx;
  __syncthreads();
  mx = fmaxf(fmaxf(red[0], red[1]), fmaxf(red[2], red[3]));
  const float e0 = __expf(v0 - mx), e1 = __expf(v1 - mx);
  float sum = e0 + e1;
#pragma unroll
  for (int off = 32; off >= 1; off >>= 1) sum += __shfl_xor(sum, off);
  if (lane == 0) red[4 + wave] = sum;
  __syncthreads();
  sum = (red[4] + red[5]) + (red[6] + red[7]);
  const float inv = 1.f / sum;
  w[t] = e0 * inv;
  w[t + 256] = e1 * inv;
  __syncthreads();
  // applied: thread (hp, sq) sums s in [sq*64, sq*64+64) for h-pair hp
  const int hp = t & 31, sq = t >> 5;
  const int h = chunk * 64 + hp * 2;
  const uint32_t* base = (const uint32_t*)encb + (size_t)b * 512 + (h >> 1);
  float a0 = 0.f, a1 = 0.f;
#pragma unroll 8
  for (int s = sq * 64; s < sq * 64 + 64; ++s) {
    const uint32_t p = base[(size_t)s * 32768];
    a0 += w[s] * bf2f((uint16_t)(p & 0xffffu));
    a1 += w[s] * bf2f((uint16_t)(p >> 16));
  }
  part2[t] = make_float2(a0, a1);
  __syncthreads();
  if (t < 32) {
    a0 = 0.f; a1 = 0.f;
#pragma unroll
    for (int k = 0; k < 8; ++k) {
      const float2 pp = part2[t + 32 * k];
      a0 += pp.x; a1 += pp.y;
    }
    *(float2*)(out_applied + (size_t)b * 1024 + h) = make_float2(a0, a1);
    *(uint32_t*)(acat + (size_t)b * 2048 + 1024 + h) = pk2(a0, a1);
    *(uint32_t*)(acat + (size_t)b * 2048 + h) =
        pk2(dec[(size_t)b * 1024 + h], dec[(size_t)b * 1024 + h + 1]);
    *(float2*)(out_acc + (size_t)b * 1024 + h) = make_float2(0.f, 0.f);
  }
}

// out = tanh(out_acc), 16384 float4s: 64 blocks x 256.
__global__ __launch_bounds__(256)
void tanh_kernel(const float* __restrict__ acc, float* __restrict__ outp) {
  const int i = blockIdx.x * 256 + threadIdx.x;
  float4 v = ((const float4*)acc)[i];
  v.x = tanh_fast(v.x); v.y = tanh_fast(v.y);
  v.z = tanh_fast(v.z); v.w = tanh_fast(v.w);
  ((float4*)outp)[i] = v;
}

extern "C" void kernel_launch(void* const* d_in, const int* in_sizes, int n_in,
                              void* d_out, int out_size, void* d_ws, size_t ws_size,
                              hipStream_t stream) {
  const float* hidden  = (const float*)d_in[0];
  const float* dec     = (const float*)d_in[1];
  const float* enc     = (const float*)d_in[2];
  const float* W_attn  = (const float*)d_in[3];
  const float* b_attn  = (const float*)d_in[4];
  const float* W_attn2 = (const float*)d_in[5];
  const float* W_comb  = (const float*)d_in[7];
  const float* b_comb  = (const float*)d_in[8];
  float* outp = (float*)d_out;                 // [out 65536 | applied 65536] f32

  char* ws = (char*)d_ws;
  float*    scores = (float*)(ws + 0);             // 128 KB
  float*    U      = (float*)(ws + 131072);        // 512 KB (dead after gemm_score)
  float*    out_acc= (float*)(ws + 131072);        // 256 KB, reuses U space
  uint16_t* acat   = (uint16_t*)(ws + 655360);     // 256 KB
  uint16_t* enc_bf = (uint16_t*)(ws + 1048576);    // 64 MB
  uint16_t* Wa_bf  = (uint16_t*)(ws + 68157440);   // 4 MB  [2048,1024]
  uint16_t* Wc_bf  = (uint16_t*)(ws + 72351744);   // 4 MB  [1024,2048]

  cvt_all_kernel<<<4608, 256, 0, stream>>>(enc, W_attn, W_comb, enc_bf, Wa_bf,
                                           Wc_bf, scores, U, b_attn);
  gemm_u_kernel<<<dim3(16, 4), 256, 0, stream>>>(hidden, W_attn, U);
  gemm_score_kernel<<<1024, 512, 0, stream>>>(enc_bf, Wa_bf, scores, U, W_attn2);
  applied_kernel<<<dim3(64, 16), 256, 0, stream>>>(enc_bf, dec, scores,
                                                   outp + 65536, acat, out_acc);
  gemm_comb_kernel<16><<<dim3(1, 8, 4), 256, 0, stream>>>(
      acat, 2048, Wc_bf, 2048, 64, out_acc, b_comb);
  tanh_kernel<<<64, 256, 0, stream>>>(out_acc, outp);
}

// Round 5
// 444.288 us; speedup vs baseline: 1.0912x; 1.0168x over previous
//
#include <hip/hip_runtime.h>
#include <stdint.h>

// AttentionModule: S=512, B=64, H=1024. Inputs f32, output f32.
// R13: gemm_score BK=64 double-buffered (128 KB LDS): one vmcnt(0)+barrier
//      per 64-K iter (16 iters, half the barriers), 24 ds_reads + 64 MFMA
//      per iter in one unrolled BB so the scheduler overlaps sub-step h=1
//      reads with h=0 MFMAs. Swizzle: stored chunk = kc ^ (row&7) for the
//      128B-stride rows (2-way banks, free). Grid/epilogue from R12.
//   cvt_all: enc/Wa_right/Wc -> bf16 + scores=0 + U=b_attn (one launch)
//   gemm_u: split-K(4) atomicAdd into U
//   gemm_score: scores += sum_j tanh(enc@Wa_r.T + U)*W_attn2
//   applied: fused softmax + weighted sum + acat build + zero out_acc
//   gemm_comb: out_acc += acat @ Wc.T (+ b_comb on z==0), split-K(4)
//   tanh:   out = tanh(out_acc)

typedef __attribute__((ext_vector_type(8))) short bf16x8;
typedef __attribute__((ext_vector_type(4))) float f32x4;

__device__ __forceinline__ float bf2f(uint16_t u) {
  return __uint_as_float(((uint32_t)u) << 16);
}
__device__ __forceinline__ uint16_t f2bf(float x) {
  uint32_t u = __float_as_uint(x);
  u += 0x7fffu + ((u >> 16) & 1u);   // RNE
  return (uint16_t)(u >> 16);
}
__device__ __forceinline__ uint32_t pk2(float a, float b) {
  return (uint32_t)f2bf(a) | ((uint32_t)f2bf(b) << 16);
}
__device__ __forceinline__ uint4 cvt8(const float* __restrict__ p) {
  const float4 a = *(const float4*)p;
  const float4 b = *(const float4*)(p + 4);
  uint4 r;
  r.x = pk2(a.x, a.y); r.y = pk2(a.z, a.w);
  r.z = pk2(b.x, b.y); r.w = pk2(b.z, b.w);
  return r;
}
// tanh(x) = 1 - 2/(exp(2x)+1)
__device__ __forceinline__ float tanh_fast(float x) {
  const float e = __expf(2.f * x);
  return __builtin_fmaf(-2.f, __builtin_amdgcn_rcpf(e + 1.f), 1.f);
}
__device__ __forceinline__ void load16(const uint16_t* g, uint16_t* l) {
  __builtin_amdgcn_global_load_lds(
      (const __attribute__((address_space(1))) void*)g,
      (__attribute__((address_space(3))) void*)l, 16, 0, 0);
}

// one-shot converts + init: enc (4194304 u4) | Wa right half (262144 u4) |
// Wc (262144 u4); first 32768 threads also zero scores and prefill U=bias.
__global__ __launch_bounds__(256)
void cvt_all_kernel(const float* __restrict__ enc, const float* __restrict__ Wa,
                    const float* __restrict__ Wc,
                    uint16_t* __restrict__ enc_bf, uint16_t* __restrict__ Wa_bf,
                    uint16_t* __restrict__ Wc_bf,
                    float* __restrict__ scores, float* __restrict__ U,
                    const float* __restrict__ ba) {
  const int tid0 = blockIdx.x * 256 + threadIdx.x;
  if (tid0 < 32768) {
    scores[tid0] = 0.f;
#pragma unroll
    for (int k = 0; k < 4; ++k) {
      const int i = tid0 * 4 + k;
      U[i] = ba[i & 2047];
    }
  }
  const int stride = gridDim.x * 256;
  for (int idx = tid0; idx < 4718592; idx += stride) {
    if (idx < 4194304) {
      ((uint4*)enc_bf)[idx] = cvt8(enc + (size_t)idx * 8);
    } else if (idx < 4456448) {
      const int k = idx - 4194304;
      const int j = k >> 7, c8 = k & 127;
      ((uint4*)Wa_bf)[k] = cvt8(Wa + (size_t)j * 2048 + 1024 + c8 * 8);
    } else {
      const int k = idx - 4456448;
      ((uint4*)Wc_bf)[k] = cvt8(Wc + (size_t)k * 8);
    }
  }
}

// split-K U-GEMM: U[b,j] += hidden[b,:]@W_attn[j,:1024].T over K-slice.
// grid (16 n-blocks, 4 k-splits); U prefilled with bias by cvt_all.
__global__ __launch_bounds__(256)
void gemm_u_kernel(const float* __restrict__ A, const float* __restrict__ B32,
                   float* __restrict__ U) {
  __shared__ __align__(16) uint16_t sA[128 * 32];
  __shared__ __align__(16) uint16_t sB[128 * 32];
  const int t = threadIdx.x, lane = t & 63, wave = t >> 6;
  const int wm = wave >> 1, wn = wave & 1;
  const int bn0 = blockIdx.x * 128;
  const int kbase = blockIdx.y * 256;
  const int srow = t >> 2, scol = (t & 3) * 8;
  const int ar0 = min(srow, 63), ar1 = min(64 + srow, 63);
  f32x4 acc[4][4];
#pragma unroll
  for (int i = 0; i < 4; ++i)
#pragma unroll
    for (int j = 0; j < 4; ++j) acc[i][j] = (f32x4){0.f, 0.f, 0.f, 0.f};
  const int mrow = wm * 64 + (lane & 15);
  const int nrow = wn * 64 + (lane & 15);
  const int kq = (lane >> 4) * 8;
  for (int kk = 0; kk < 8; ++kk) {
    const int k0 = kbase + (kk << 5);
    const uint4 va0 = cvt8(A + (size_t)ar0 * 1024 + scol + k0);
    const uint4 va1 = cvt8(A + (size_t)ar1 * 1024 + scol + k0);
    const uint4 vb0 = cvt8(B32 + (size_t)(bn0 + srow) * 2048 + scol + k0);
    const uint4 vb1 = cvt8(B32 + (size_t)(bn0 + 64 + srow) * 2048 + scol + k0);
    __syncthreads();
    *(uint4*)&sA[t * 8] = va0;
    *(uint4*)&sA[2048 + t * 8] = va1;
    *(uint4*)&sB[t * 8] = vb0;
    *(uint4*)&sB[2048 + t * 8] = vb1;
    __syncthreads();
    bf16x8 af[4], bfr[4];
#pragma unroll
    for (int i = 0; i < 4; ++i) af[i] = *(const bf16x8*)&sA[(mrow + i * 16) * 32 + kq];
#pragma unroll
    for (int j = 0; j < 4; ++j) bfr[j] = *(const bf16x8*)&sB[(nrow + j * 16) * 32 + kq];
#pragma unroll
    for (int i = 0; i < 4; ++i)
#pragma unroll
      for (int j = 0; j < 4; ++j)
        acc[i][j] = __builtin_amdgcn_mfma_f32_16x16x32_bf16(af[i], bfr[j], acc[i][j], 0, 0, 0);
  }
  const int colb = lane & 15, rquad = lane >> 4;
#pragma unroll
  for (int i = 0; i < 4; ++i)
#pragma unroll
    for (int r = 0; r < 4; ++r) {
      const int gm = wm * 64 + i * 16 + rquad * 4 + r;
      if (gm < 64) {
#pragma unroll
        for (int j = 0; j < 4; ++j) {
          const int gn = bn0 + wn * 64 + j * 16 + colb;
          atomicAdd(&U[gm * 2048 + gn], acc[i][j][r]);
        }
      }
    }
}

// ---- gemm_score: 256x256 tile, 8 waves, wave-tile 128x64, BK=64 dbuf.
// LDS tiles [256 rows][64 cols] bf16 (128 B row stride), stored 16B-chunk
// kc holds global chunk kc ^ (row&7) -> fragment reads 2-way banked (free).
// Per iter: issue 8 stage DMAs (next buf) | 24 ds_read_b128 | 64 MFMA |
// vmcnt(0)+barrier. 16 iters fully unrolled. Grid 1024 1-D XCD-chunked.
// Epilogue: atomicAdd(scores[gm], sum_n tanh(acc + U[gm&63,gn]) * w2[gn]).
__global__ __launch_bounds__(512, 2)
void gemm_score_kernel(const uint16_t* __restrict__ A,
                       const uint16_t* __restrict__ Bm,
                       float* __restrict__ outf,
                       const float* __restrict__ Ubias,
                       const float* __restrict__ bias) {
  __shared__ __align__(16) uint16_t lds[2][2][16384];  // 128 KB dbuf

  const int t = threadIdx.x, lane = t & 63, wave = t >> 6;
  const int wm = wave >> 2, wn = wave & 3;   // 2m x 4n wave grid
  const int wid = blockIdx.x;
  const int xcd = wid & 7, q = wid >> 3;     // q in [0,128)
  const int bm0 = (xcd * 16 + (q >> 3)) * 256;
  const int bn0 = (q & 7) * 256;

  // staging map: operand tile = 2048 slots of 16B; thread covers slots
  // s = qq*512 + t. slot -> row=s>>3, kc=s&7, global chunk kc^(row&7).
  const uint16_t* gpA[4];
  const uint16_t* gpB[4];
  int sb[4];
#pragma unroll
  for (int qq = 0; qq < 4; ++qq) {
    const int s = qq * 512 + t;
    const int r = s >> 3, kc = s & 7;
    const int g = kc ^ (r & 7);
    gpA[qq] = A + (size_t)(bm0 + r) * 1024 + g * 8;
    gpB[qq] = Bm + (size_t)(bn0 + r) * 1024 + g * 8;
    sb[qq] = (qq * 512 + wave * 64) * 8;   // wave-uniform LDS base (elems)
  }

  f32x4 acc[8][4];
#pragma unroll
  for (int i = 0; i < 8; ++i)
#pragma unroll
    for (int j = 0; j < 4; ++j) acc[i][j] = (f32x4){0.f, 0.f, 0.f, 0.f};

  // fragment read offsets: row = wX*base + i*16 + (lane&15); desired chunk
  // for K-half h = h*4 + (lane>>4); stored chunk = desired ^ (lane&7)
  // (row&7 == lane&7 since all other row terms are multiples of 8).
  const int rl = lane & 15, kqh = lane >> 4, l7 = lane & 7;
  const int cx0 = (kqh ^ l7) * 8;
  const int cx1 = ((4 + kqh) ^ l7) * 8;
  const int abase = (wm * 128 + rl) * 64;
  const int bbase = (wn * 64 + rl) * 64;

  // prologue: stage tile 0 into buf 0, drain, barrier
#pragma unroll
  for (int qq = 0; qq < 4; ++qq) {
    load16(gpA[qq], &lds[0][0][sb[qq]]);
    load16(gpB[qq], &lds[0][1][sb[qq]]);
  }
  asm volatile("s_waitcnt vmcnt(0)" ::: "memory");
  __builtin_amdgcn_s_barrier();

  constexpr int NT = 16;
#pragma unroll
  for (int kt = 0; kt < NT; ++kt) {
    const int cb = kt & 1;
    if (kt + 1 < NT) {
      const int nb = cb ^ 1;
      const int ko = (kt + 1) * 64;
#pragma unroll
      for (int qq = 0; qq < 4; ++qq) {
        load16(gpA[qq] + ko, &lds[nb][0][sb[qq]]);
        load16(gpB[qq] + ko, &lds[nb][1][sb[qq]]);
      }
    }
    const uint16_t* sA = lds[cb][0];
    const uint16_t* sB = lds[cb][1];
    // sub-step h=0
    {
      bf16x8 af[8], bfr[4];
#pragma unroll
      for (int i = 0; i < 8; ++i) af[i] = *(const bf16x8*)&sA[abase + i * 1024 + cx0];
#pragma unroll
      for (int j = 0; j < 4; ++j) bfr[j] = *(const bf16x8*)&sB[bbase + j * 1024 + cx0];
#pragma unroll
      for (int i = 0; i < 8; ++i)
#pragma unroll
        for (int j = 0; j < 4; ++j)
          acc[i][j] = __builtin_amdgcn_mfma_f32_16x16x32_bf16(af[i], bfr[j], acc[i][j], 0, 0, 0);
    }
    // sub-step h=1 (reads independent of h=0 MFMAs -> scheduler overlaps)
    {
      bf16x8 af[8], bfr[4];
#pragma unroll
      for (int i = 0; i < 8; ++i) af[i] = *(const bf16x8*)&sA[abase + i * 1024 + cx1];
#pragma unroll
      for (int j = 0; j < 4; ++j) bfr[j] = *(const bf16x8*)&sB[bbase + j * 1024 + cx1];
#pragma unroll
      for (int i = 0; i < 8; ++i)
#pragma unroll
        for (int j = 0; j < 4; ++j)
          acc[i][j] = __builtin_amdgcn_mfma_f32_16x16x32_bf16(af[i], bfr[j], acc[i][j], 0, 0, 0);
    }
    if (kt + 1 < NT) {
      // next buf's DMAs had the whole iter to land; drain is cheap
      asm volatile("s_waitcnt vmcnt(0)" ::: "memory");
      __builtin_amdgcn_s_barrier();
    }
  }

  const int colb = lane & 15, rquad = lane >> 4;
  float w2f[4];
#pragma unroll
  for (int j = 0; j < 4; ++j) w2f[j] = bias[bn0 + wn * 64 + j * 16 + colb];
#pragma unroll
  for (int i = 0; i < 8; ++i) {
#pragma unroll
    for (int r = 0; r < 4; ++r) {
      const int gm = bm0 + wm * 128 + i * 16 + rquad * 4 + r;  // = s*64 + b
      const int bb = gm & 63;
      float p = 0.f;
#pragma unroll
      for (int j = 0; j < 4; ++j) {
        const float u = Ubias[bb * 2048 + bn0 + wn * 64 + j * 16 + colb];
        p += tanh_fast(acc[i][j][r] + u) * w2f[j];
      }
      p += __shfl_xor(p, 1);
      p += __shfl_xor(p, 2);
      p += __shfl_xor(p, 4);
      p += __shfl_xor(p, 8);
      if (colb == 0) atomicAdd(outf + gm, p);
    }
  }
}

// ---- small split-K GEMM for out = acat @ Wc.T (tri-buffer, proven).
// grid (1, N/128, Ksplit), K-slice = NT*32 per z. atomicAdd into pre-zeroed
// f32 accumulator (+ bias on z==0).
template <int NT>
__global__ __launch_bounds__(256)
void gemm_comb_kernel(const uint16_t* __restrict__ A, int lda,
                      const uint16_t* __restrict__ Bm, int ldb,
                      int M, float* __restrict__ outf,
                      const float* __restrict__ bias) {
  __shared__ __align__(16) uint16_t lds[3][2][4096];  // 48 KB tri-buffer

  const int t = threadIdx.x, lane = t & 63, wave = t >> 6;
  const int wm = wave >> 1, wn = wave & 1;
  const int bm0 = 0;
  const int bn0 = blockIdx.y * 128;
  const int kbase = blockIdx.z * (NT * 32);

  const uint16_t* gpA[2];
  const uint16_t* gpB[2];
  int sb[2];
#pragma unroll
  for (int q = 0; q < 2; ++q) {
    const int s = q * 256 + t;
    const int r = s >> 2, kc = s & 3;
    const int g = kc ^ ((r >> 1) & 3);
    gpA[q] = A + (size_t)min(bm0 + r, M - 1) * lda + kbase + g * 8;
    gpB[q] = Bm + (size_t)(bn0 + r) * ldb + kbase + g * 8;
    sb[q] = (q * 256 + wave * 64) * 8;
  }

  f32x4 acc[4][4];
#pragma unroll
  for (int i = 0; i < 4; ++i)
#pragma unroll
    for (int j = 0; j < 4; ++j) acc[i][j] = (f32x4){0.f, 0.f, 0.f, 0.f};

  const int swz = ((lane >> 1) & 3) << 3;
  const int kq = ((lane >> 4) * 8) ^ swz;
  const int aoff = (wm * 64 + (lane & 15)) * 32 + kq;
  const int boff = (wn * 64 + (lane & 15)) * 32 + kq;

#pragma unroll
  for (int q = 0; q < 2; ++q) {
    load16(gpA[q], &lds[0][0][sb[q]]);
    load16(gpB[q], &lds[0][1][sb[q]]);
  }
#pragma unroll
  for (int q = 0; q < 2; ++q) {
    load16(gpA[q] + 32, &lds[1][0][sb[q]]);
    load16(gpB[q] + 32, &lds[1][1][sb[q]]);
  }
  asm volatile("s_waitcnt vmcnt(4)" ::: "memory");
  __builtin_amdgcn_s_barrier();

#pragma unroll
  for (int kt = 0; kt < NT; ++kt) {
    const int bufc = kt % 3;
    if (kt + 2 < NT) {
      const int nb = (kt + 2) % 3;
      const int kpre = (kt + 2) * 32;
#pragma unroll
      for (int q = 0; q < 2; ++q) {
        load16(gpA[q] + kpre, &lds[nb][0][sb[q]]);
        load16(gpB[q] + kpre, &lds[nb][1][sb[q]]);
      }
    }
    const uint16_t* sA = lds[bufc][0];
    const uint16_t* sB = lds[bufc][1];
    bf16x8 af[4], bfr[4];
#pragma unroll
    for (int i = 0; i < 4; ++i) af[i] = *(const bf16x8*)&sA[aoff + i * 512];
#pragma unroll
    for (int j = 0; j < 4; ++j) bfr[j] = *(const bf16x8*)&sB[boff + j * 512];
#pragma unroll
    for (int i = 0; i < 4; ++i)
#pragma unroll
      for (int j = 0; j < 4; ++j)
        acc[i][j] = __builtin_amdgcn_mfma_f32_16x16x32_bf16(af[i], bfr[j], acc[i][j], 0, 0, 0);
    if (kt + 2 < NT) {
      asm volatile("s_waitcnt vmcnt(4) lgkmcnt(0)" ::: "memory");
      __builtin_amdgcn_s_barrier();
    } else if (kt + 1 < NT) {
      asm volatile("s_waitcnt vmcnt(0) lgkmcnt(0)" ::: "memory");
      __builtin_amdgcn_s_barrier();
    }
  }

  const int colb = lane & 15, rquad = lane >> 4;
  const float bsc = (blockIdx.z == 0) ? 1.f : 0.f;
#pragma unroll
  for (int i = 0; i < 4; ++i)
#pragma unroll
    for (int r = 0; r < 4; ++r) {
      const int gm = bm0 + wm * 64 + i * 16 + rquad * 4 + r;
      if (gm < M) {
#pragma unroll
        for (int j = 0; j < 4; ++j) {
          const int gn = bn0 + wn * 64 + j * 16 + colb;
          atomicAdd(outf + gm * 1024 + gn, acc[i][j][r] + bsc * bias[gn]);
        }
      }
    }
}

// fused softmax + applied + acat + out_acc zeroing.
// grid (64 b, 16 h-chunks) x 256 thr; within a block the 512 s-values are
// split 8-way (sq = t>>5) and tree-reduced in LDS -> 1024 blocks (4/CU).
__global__ __launch_bounds__(256)
void applied_kernel(const uint16_t* __restrict__ encb, const float* __restrict__ dec,
                    const float* __restrict__ scores,
                    float* __restrict__ out_applied, uint16_t* __restrict__ acat,
                    float* __restrict__ out_acc) {
  const int b = blockIdx.x, chunk = blockIdx.y, t = threadIdx.x;
  const int wave = t >> 6, lane = t & 63;
  __shared__ float w[512];
  __shared__ float red[8];
  __shared__ float2 part2[256];
  // softmax over s for this b (each thread owns s=t and s=t+256)
  float v0 = scores[(size_t)t * 64 + b];
  float v1 = scores[(size_t)(t + 256) * 64 + b];
  float mx = fmaxf(v0, v1);
#pragma unroll
  for (int off = 32; off >= 1; off >>= 1) mx = fmaxf(mx, __shfl_xor(mx, off));
  if (lane == 0) red[wave] = mx;
  __syncthreads();
  mx = fmaxf(fmaxf(red[0], red[1]), fmaxf(red[2], red[3]));
  const float e0 = __expf(v0 - mx), e1 = __expf(v1 - mx);
  float sum = e0 + e1;
#pragma unroll
  for (int off = 32; off >= 1; off >>= 1) sum += __shfl_xor(sum, off);
  if (lane == 0) red[4 + wave] = sum;
  __syncthreads();
  sum = (red[4] + red[5]) + (red[6] + red[7]);
  const float inv = 1.f / sum;
  w[t] = e0 * inv;
  w[t + 256] = e1 * inv;
  __syncthreads();
  // applied: thread (hp, sq) sums s in [sq*64, sq*64+64) for h-pair hp
  const int hp = t & 31, sq = t >> 5;
  const int h = chunk * 64 + hp * 2;
  const uint32_t* base = (const uint32_t*)encb + (size_t)b * 512 + (h >> 1);
  float a0 = 0.f, a1 = 0.f;
#pragma unroll 8
  for (int s = sq * 64; s < sq * 64 + 64; ++s) {
    const uint32_t p = base[(size_t)s * 32768];
    a0 += w[s] * bf2f((uint16_t)(p & 0xffffu));
    a1 += w[s] * bf2f((uint16_t)(p >> 16));
  }
  part2[t] = make_float2(a0, a1);
  __syncthreads();
  if (t < 32) {
    a0 = 0.f; a1 = 0.f;
#pragma unroll
    for (int k = 0; k < 8; ++k) {
      const float2 pp = part2[t + 32 * k];
      a0 += pp.x; a1 += pp.y;
    }
    *(float2*)(out_applied + (size_t)b * 1024 + h) = make_float2(a0, a1);
    *(uint32_t*)(acat + (size_t)b * 2048 + 1024 + h) = pk2(a0, a1);
    *(uint32_t*)(acat + (size_t)b * 2048 + h) =
        pk2(dec[(size_t)b * 1024 + h], dec[(size_t)b * 1024 + h + 1]);
    *(float2*)(out_acc + (size_t)b * 1024 + h) = make_float2(0.f, 0.f);
  }
}

// out = tanh(out_acc), 16384 float4s: 64 blocks x 256.
__global__ __launch_bounds__(256)
void tanh_kernel(const float* __restrict__ acc, float* __restrict__ outp) {
  const int i = blockIdx.x * 256 + threadIdx.x;
  float4 v = ((const float4*)acc)[i];
  v.x = tanh_fast(v.x); v.y = tanh_fast(v.y);
  v.z = tanh_fast(v.z); v.w = tanh_fast(v.w);
  ((float4*)outp)[i] = v;
}

extern "C" void kernel_launch(void* const* d_in, const int* in_sizes, int n_in,
                              void* d_out, int out_size, void* d_ws, size_t ws_size,
                              hipStream_t stream) {
  const float* hidden  = (const float*)d_in[0];
  const float* dec     = (const float*)d_in[1];
  const float* enc     = (const float*)d_in[2];
  const float* W_attn  = (const float*)d_in[3];
  const float* b_attn  = (const float*)d_in[4];
  const float* W_attn2 = (const float*)d_in[5];
  const float* W_comb  = (const float*)d_in[7];
  const float* b_comb  = (const float*)d_in[8];
  float* outp = (float*)d_out;                 // [out 65536 | applied 65536] f32

  char* ws = (char*)d_ws;
  float*    scores = (float*)(ws + 0);             // 128 KB
  float*    U      = (float*)(ws + 131072);        // 512 KB (dead after gemm_score)
  float*    out_acc= (float*)(ws + 131072);        // 256 KB, reuses U space
  uint16_t* acat   = (uint16_t*)(ws + 655360);     // 256 KB
  uint16_t* enc_bf = (uint16_t*)(ws + 1048576);    // 64 MB
  uint16_t* Wa_bf  = (uint16_t*)(ws + 68157440);   // 4 MB  [2048,1024]
  uint16_t* Wc_bf  = (uint16_t*)(ws + 72351744);   // 4 MB  [1024,2048]

  cvt_all_kernel<<<4608, 256, 0, stream>>>(enc, W_attn, W_comb, enc_bf, Wa_bf,
                                           Wc_bf, scores, U, b_attn);
  gemm_u_kernel<<<dim3(16, 4), 256, 0, stream>>>(hidden, W_attn, U);
  gemm_score_kernel<<<1024, 512, 0, stream>>>(enc_bf, Wa_bf, scores, U, W_attn2);
  applied_kernel<<<dim3(64, 16), 256, 0, stream>>>(enc_bf, dec, scores,
                                                   outp + 65536, acat, out_acc);
  gemm_comb_kernel<16><<<dim3(1, 8, 4), 256, 0, stream>>>(
      acat, 2048, Wc_bf, 2048, 64, out_acc, b_comb);
  tanh_kernel<<<64, 256, 0, stream>>>(out_acc, outp);
}